// Round 5
// baseline (1104.659 us; speedup 1.0000x reference)
//
#include <hip/hip_runtime.h>

#define EPS 1e-5f

typedef __attribute__((ext_vector_type(8))) short short8;
typedef __attribute__((ext_vector_type(4))) float floatx4;
typedef __attribute__((ext_vector_type(4))) unsigned short ushortx4;
typedef __attribute__((ext_vector_type(2))) unsigned short ushortx2;

__device__ __forceinline__ unsigned short f2bf(float f) {
    unsigned u = __float_as_uint(f);
    unsigned r = (u + 0x7FFFu + ((u >> 16) & 1u)) >> 16;
    return (unsigned short)r;
}
__device__ __forceinline__ float bf2f(unsigned short h) {
    return __uint_as_float((unsigned)h << 16);
}

// ---------------------------------------------------------------- utilities
__global__ void zero_kernel(int* __restrict__ hist2, float* __restrict__ stats,
                            int n_hist, int n_stats) {
    int i = blockIdx.x * 256 + threadIdx.x;
    if (i < n_hist)  hist2[i] = 0;
    if (i < n_stats) stats[i] = 0.0f;
}

// per-chunk LDS histogram of buckets (row>>7), flushed to hist2[b*8+g], g=blockIdx&7
__global__ __launch_bounds__(256) void bucket_hist_kernel(const int* __restrict__ erow,
                                                          int* __restrict__ hist2,
                                                          int E, int chunk, int nb) {
    __shared__ int cnt[1024];
    int g = blockIdx.x & 7;
    for (int i = threadIdx.x; i < nb; i += 256) cnt[i] = 0;
    __syncthreads();
    int base = blockIdx.x * chunk;
    int end = min(base + chunk, E);
    for (int j = base + threadIdx.x; j < end; j += 256)
        atomicAdd(&cnt[erow[j] >> 7], 1);
    __syncthreads();
    for (int i = threadIdx.x; i < nb; i += 256) {
        int c = cnt[i];
        if (c) atomicAdd(&hist2[i * 8 + g], c);
    }
}

// single-block exclusive scan over hist2[nb*8] -> cursor2 + bucket_start
__global__ __launch_bounds__(1024) void bucket_scan_kernel(const int* __restrict__ hist2,
                                                           int* __restrict__ cursor2,
                                                           int* __restrict__ bucket_start,
                                                           int* __restrict__ row_start,
                                                           int nb, int n, int E) {
    __shared__ int lds[1024];
    int t = threadIdx.x;
    int total = nb * 8;
    int per = (total + 1023) >> 10;
    int s0 = t * per, s1 = min(s0 + per, total);
    int sum = 0;
    for (int i = s0; i < s1; i++) sum += hist2[i];
    lds[t] = sum;
    __syncthreads();
    for (int off = 1; off < 1024; off <<= 1) {
        int v = (t >= off) ? lds[t - off] : 0;
        __syncthreads();
        lds[t] += v;
        __syncthreads();
    }
    int run = lds[t] - sum;  // exclusive prefix
    for (int i = s0; i < s1; i++) {
        cursor2[i] = run;
        if ((i & 7) == 0) bucket_start[i >> 3] = run;
        run += hist2[i];
    }
    if (t == 0) { bucket_start[nb] = E; row_start[n] = E; }
}

// pass 1: append edges into per-(bucket, group) sub-regions; key packs localrow in bits 17..23
__global__ __launch_bounds__(256) void pass1_scatter_kernel(const int* __restrict__ erow,
                                                            const int* __restrict__ ecol,
                                                            const float* __restrict__ ev,
                                                            int* __restrict__ cursor2,
                                                            int2* __restrict__ tmp,
                                                            int E, int chunk) {
    int g = blockIdx.x & 7;
    int base = blockIdx.x * chunk;
    int end = min(base + chunk, E);
    for (int j = base + threadIdx.x; j < end; j += 256) {
        int r = erow[j];
        int b = r >> 7, lr = r & 127;
        int key = ecol[j] | (lr << 17);
        int p = atomicAdd(&cursor2[b * 8 + g], 1);
        tmp[p] = make_int2(key, __float_as_int(ev[j]));
    }
}

// pass 2: one block per bucket. LDS row counts -> scan -> row_start + exact CSR placement.
__global__ __launch_bounds__(256) void pass2_kernel(const int2* __restrict__ tmp,
                                                    const int* __restrict__ bucket_start,
                                                    int* __restrict__ row_start,
                                                    int2* __restrict__ edges, int n) {
    __shared__ int cnt[128], scn[128], cur[128];
    int b = blockIdx.x, t = threadIdx.x;
    int bstart = bucket_start[b], bend = bucket_start[b + 1];
    if (t < 128) cnt[t] = 0;
    __syncthreads();
    for (int j = bstart + t; j < bend; j += 256)
        atomicAdd(&cnt[((unsigned)tmp[j].x) >> 17], 1);
    __syncthreads();
    if (t < 128) scn[t] = cnt[t];
    __syncthreads();
#pragma unroll
    for (int off = 1; off < 128; off <<= 1) {
        int v = 0;
        if (t < 128 && t >= off) v = scn[t - off];
        __syncthreads();
        if (t < 128) scn[t] += v;
        __syncthreads();
    }
    if (t < 128) {
        int pref = scn[t] - cnt[t];   // exclusive prefix within bucket
        cur[t] = pref;
        int r = b * 128 + t;
        if (r <= n) row_start[r] = bstart + pref;
    }
    __syncthreads();
    for (int j = bstart + t; j < bend; j += 256) {
        int2 e = tmp[j];
        int lr = ((unsigned)e.x) >> 17;
        int pos = atomicAdd(&cur[lr], 1);
        edges[bstart + pos] = make_int2(e.x & 0x1FFFF, e.y);
    }
}

// ---------------------------------------------------------------- W1 -> split bf16 transposed [256][512]
__global__ void prep_w1_kernel(const float* __restrict__ W1,
                               unsigned short* __restrict__ Bhi,
                               unsigned short* __restrict__ Blo) {
    int idx = blockIdx.x * 256 + threadIdx.x;   // 131072 total
    int nn = idx >> 9, k = idx & 511;
    float w = W1[(size_t)k * 256 + nn];
    unsigned short hi = f2bf(w);
    Bhi[idx] = hi;
    Blo[idx] = f2bf(w - bf2f(hi));
}

// ---------------------------------------------------------------- W2 -> split bf16 transposed [64][256]
__global__ void prep_w2_kernel(const float* __restrict__ W2,
                               unsigned short* __restrict__ Bhi,
                               unsigned short* __restrict__ Blo) {
    int idx = blockIdx.x * 256 + threadIdx.x;   // 16384 total
    int nn = idx >> 8, k = idx & 255;
    float w = W2[(size_t)k * 64 + nn];
    unsigned short hi = f2bf(w);
    Bhi[idx] = hi;
    Blo[idx] = f2bf(w - bf2f(hi));
}

// ---------------------------------------------------------------- GEMM1 (split-bf16 MFMA, ~fp32 exact):
// h0[M,256](bf16) = A[M,512](fp32) @ W1.  Single N-pass: block tile 128x256, A read ONCE.
// 4 waves 2x2: wave tile 64x128 = 4x8 MFMA 16x16x32, 3 terms each.
__global__ __launch_bounds__(256, 1) void gemm1_mfma_kernel(const float* __restrict__ A,
                                                            const unsigned short* __restrict__ Bhi,
                                                            const unsigned short* __restrict__ Blo,
                                                            unsigned short* __restrict__ H0, int M) {
    __shared__ unsigned short AsH[128][32];
    __shared__ unsigned short AsL[128][32];
    __shared__ unsigned short BsH[256][32];
    __shared__ unsigned short BsL[256][32];
    int tid  = threadIdx.x;
    int lane = tid & 63, w = tid >> 6;
    int wm = w & 1, wn = w >> 1;           // wave tile: rows wm*64, cols wn*128
    int rowBase = blockIdx.x * 128;

    floatx4 acc[4][8];
#pragma unroll
    for (int i = 0; i < 4; i++)
#pragma unroll
        for (int j = 0; j < 8; j++)
#pragma unroll
            for (int r = 0; r < 4; r++) acc[i][j][r] = 0.0f;

    int r    = tid >> 1;        // 0..127 A staging row
    int half = tid & 1;
    bool aval = (rowBase + r) < M;
    const float* aptr = A + (size_t)(rowBase + r) * 512 + half * 16;
    const unsigned short* bhptr = Bhi + (size_t)tid * 512;   // tid = output col 0..255
    const unsigned short* blptr = Blo + (size_t)tid * 512;

    int cl = lane & 15, quad = lane >> 4;
    int q8 = quad * 8;

    for (int k0 = 0; k0 < 512; k0 += 32) {
        // ---- stage A (fp32 -> bf16 hi+lo): 16 floats per thread
        float f[16];
        if (aval) {
            *(float4*)&f[0]  = *(const float4*)(aptr + k0);
            *(float4*)&f[4]  = *(const float4*)(aptr + k0 + 4);
            *(float4*)&f[8]  = *(const float4*)(aptr + k0 + 8);
            *(float4*)&f[12] = *(const float4*)(aptr + k0 + 12);
        } else {
#pragma unroll
            for (int t = 0; t < 16; t++) f[t] = 0.0f;
        }
        union { unsigned short s[16]; uint4 q[2]; } ph, pl;
#pragma unroll
        for (int t = 0; t < 16; t++) {
            unsigned short hi = f2bf(f[t]);
            ph.s[t] = hi;
            pl.s[t] = f2bf(f[t] - bf2f(hi));
        }
        *(uint4*)&AsH[r][half * 16]     = ph.q[0];
        *(uint4*)&AsH[r][half * 16 + 8] = ph.q[1];
        *(uint4*)&AsL[r][half * 16]     = pl.q[0];
        *(uint4*)&AsL[r][half * 16 + 8] = pl.q[1];
        // ---- stage B: each thread stages its output-col row, 32 k-elems (64 B) hi+lo
        *(uint4*)&BsH[tid][0]  = *(const uint4*)(bhptr + k0);
        *(uint4*)&BsH[tid][8]  = *(const uint4*)(bhptr + k0 + 8);
        *(uint4*)&BsH[tid][16] = *(const uint4*)(bhptr + k0 + 16);
        *(uint4*)&BsH[tid][24] = *(const uint4*)(bhptr + k0 + 24);
        *(uint4*)&BsL[tid][0]  = *(const uint4*)(blptr + k0);
        *(uint4*)&BsL[tid][8]  = *(const uint4*)(blptr + k0 + 8);
        *(uint4*)&BsL[tid][16] = *(const uint4*)(blptr + k0 + 16);
        *(uint4*)&BsL[tid][24] = *(const uint4*)(blptr + k0 + 24);
        __syncthreads();

        short8 ah[4], al[4];
#pragma unroll
        for (int mt = 0; mt < 4; mt++) {
            ah[mt] = *(short8*)&AsH[wm * 64 + mt * 16 + cl][q8];
            al[mt] = *(short8*)&AsL[wm * 64 + mt * 16 + cl][q8];
        }
#pragma unroll
        for (int nt = 0; nt < 8; nt++) {
            short8 bh = *(short8*)&BsH[wn * 128 + nt * 16 + cl][q8];
            short8 bl = *(short8*)&BsL[wn * 128 + nt * 16 + cl][q8];
#pragma unroll
            for (int mt = 0; mt < 4; mt++) {
                acc[mt][nt] = __builtin_amdgcn_mfma_f32_16x16x32_bf16(ah[mt], bh, acc[mt][nt], 0, 0, 0);
                acc[mt][nt] = __builtin_amdgcn_mfma_f32_16x16x32_bf16(al[mt], bh, acc[mt][nt], 0, 0, 0);
                acc[mt][nt] = __builtin_amdgcn_mfma_f32_16x16x32_bf16(ah[mt], bl, acc[mt][nt], 0, 0, 0);
            }
        }
        __syncthreads();
    }

    // epilogue: C/D layout col=lane&15, row=quad*4+reg ; store bf16
#pragma unroll
    for (int mt = 0; mt < 4; mt++) {
#pragma unroll
        for (int reg = 0; reg < 4; reg++) {
            int gr = rowBase + wm * 64 + mt * 16 + quad * 4 + reg;
            if (gr < M) {
#pragma unroll
                for (int nt = 0; nt < 8; nt++) {
                    H0[(size_t)gr * 256 + wn * 128 + nt * 16 + cl] = f2bf(acc[mt][nt][reg]);
                }
            }
        }
    }
}

// ---------------------------------------------------------------- SpMM1 (F=256): wave per row, bf16 gather -> bf16 out
__global__ __launch_bounds__(256) void agg1_kernel(const unsigned short* __restrict__ H0,
                                                   const int* __restrict__ rs,
                                                   const int2* __restrict__ edges,
                                                   unsigned short* __restrict__ H1, int n) {
    int w = threadIdx.x >> 6, lane = threadIdx.x & 63;
    int i = blockIdx.x * 4 + w;
    if (i >= n) return;
    int start = rs[i], end = rs[i + 1];
    int fo = lane << 2;
    float4 acc = make_float4(0.f, 0.f, 0.f, 0.f);
    int j = start;
    for (; j + 8 <= end; j += 8) {
        int2 e[8];
        ushortx4 u[8];
#pragma unroll
        for (int t = 0; t < 8; t++) e[t] = edges[j + t];
#pragma unroll
        for (int t = 0; t < 8; t++)
            u[t] = *(const ushortx4*)(H0 + (size_t)e[t].x * 256 + fo);
#pragma unroll
        for (int t = 0; t < 8; t++) {
            float v = __int_as_float(e[t].y);
            acc.x += v * bf2f(u[t].x);
            acc.y += v * bf2f(u[t].y);
            acc.z += v * bf2f(u[t].z);
            acc.w += v * bf2f(u[t].w);
        }
    }
    for (; j < end; j++) {
        int2 e = edges[j];
        float v = __int_as_float(e.y);
        ushortx4 u = *(const ushortx4*)(H0 + (size_t)e.x * 256 + fo);
        acc.x += v * bf2f(u.x);
        acc.y += v * bf2f(u.y);
        acc.z += v * bf2f(u.z);
        acc.w += v * bf2f(u.w);
    }
    ushortx4 o;
    o.x = f2bf(fmaxf(acc.x, 0.f)); o.y = f2bf(fmaxf(acc.y, 0.f));
    o.z = f2bf(fmaxf(acc.z, 0.f)); o.w = f2bf(fmaxf(acc.w, 0.f));
    *(ushortx4*)(H1 + (size_t)i * 256 + fo) = o;
}

// ---------------------------------------------------------------- column stats F=256 (bf16 input)
__global__ __launch_bounds__(256) void colstats1_kernel(const unsigned short* __restrict__ H1,
                                                        float* __restrict__ sums,
                                                        float* __restrict__ sumsq,
                                                        int n, int rpb) {
    int tid = threadIdx.x;
    int r0 = blockIdx.x * rpb;
    int r1 = min(r0 + rpb, n);
    float s = 0.f, q = 0.f;
    for (int rr = r0; rr < r1; rr++) {
        float v = bf2f(H1[(size_t)rr * 256 + tid]);
        s += v; q += v * v;
    }
    atomicAdd(&sums[tid], s);
    atomicAdd(&sumsq[tid], q);
}

__global__ void bnparams_kernel(const float* __restrict__ sums, const float* __restrict__ sumsq,
                                const float* __restrict__ gamma, const float* __restrict__ beta,
                                float* __restrict__ scale, float* __restrict__ shift,
                                int C, float invN) {
    int c = threadIdx.x;
    if (c < C) {
        float mean = sums[c] * invN;
        float var  = sumsq[c] * invN - mean * mean;
        float rstd = rsqrtf(var + EPS);
        float sc   = gamma[c] * rstd;
        scale[c] = sc;
        shift[c] = beta[c] - mean * sc;
    }
}

// ---------------------------------------------------------------- GEMM2 (MFMA): h2[M,64](bf16) = relu(bn1(h1)) @ W2
// Block tile 128x64, 4 waves 2x2: wave tile 64x32 = 4x2 MFMA tiles, W2 split-bf16 3-term.
__global__ __launch_bounds__(256) void gemm2_mfma_kernel(const unsigned short* __restrict__ H1,
                                                         const unsigned short* __restrict__ Bhi,
                                                         const unsigned short* __restrict__ Blo,
                                                         const float* __restrict__ scale1,
                                                         const float* __restrict__ shift1,
                                                         unsigned short* __restrict__ H2, int M) {
    __shared__ unsigned short As[128][32];
    __shared__ unsigned short BsH[64][32];
    __shared__ unsigned short BsL[64][32];
    int tid  = threadIdx.x;
    int lane = tid & 63, w = tid >> 6;
    int wm = w & 1, wn = w >> 1;          // wave tile: rows wm*64, cols wn*32
    int rowBase = blockIdx.x * 128;

    floatx4 acc[4][2];
#pragma unroll
    for (int i = 0; i < 4; i++)
#pragma unroll
        for (int j = 0; j < 2; j++)
#pragma unroll
            for (int r = 0; r < 4; r++) acc[i][j][r] = 0.0f;

    int r    = tid >> 1;
    int half = tid & 1;
    bool aval = (rowBase + r) < M;
    const unsigned short* aptr = H1 + (size_t)(rowBase + r) * 256 + half * 16;

    int cl = lane & 15, quad = lane >> 4;
    int q8 = quad * 8;

    for (int k0 = 0; k0 < 256; k0 += 32) {
        // ---- stage A: 16 bf16, apply BN1 scale/shift + relu, back to bf16
        union { unsigned short s[16]; uint4 q[2]; } pa;
        if (aval) {
            uint4 u0 = *(const uint4*)(aptr + k0);
            uint4 u1 = *(const uint4*)(aptr + k0 + 8);
            unsigned short raw[16];
            *(uint4*)&raw[0] = u0;
            *(uint4*)&raw[8] = u1;
            int kb = k0 + half * 16;
            float4 sc0 = *(const float4*)(scale1 + kb);
            float4 sc1 = *(const float4*)(scale1 + kb + 4);
            float4 sc2 = *(const float4*)(scale1 + kb + 8);
            float4 sc3 = *(const float4*)(scale1 + kb + 12);
            float4 sh0 = *(const float4*)(shift1 + kb);
            float4 sh1 = *(const float4*)(shift1 + kb + 4);
            float4 sh2 = *(const float4*)(shift1 + kb + 8);
            float4 sh3 = *(const float4*)(shift1 + kb + 12);
            float scv[16] = {sc0.x, sc0.y, sc0.z, sc0.w, sc1.x, sc1.y, sc1.z, sc1.w,
                             sc2.x, sc2.y, sc2.z, sc2.w, sc3.x, sc3.y, sc3.z, sc3.w};
            float shv[16] = {sh0.x, sh0.y, sh0.z, sh0.w, sh1.x, sh1.y, sh1.z, sh1.w,
                             sh2.x, sh2.y, sh2.z, sh2.w, sh3.x, sh3.y, sh3.z, sh3.w};
#pragma unroll
            for (int t = 0; t < 16; t++) {
                float vv = bf2f(raw[t]) * scv[t] + shv[t];
                pa.s[t] = f2bf(fmaxf(vv, 0.0f));
            }
        } else {
#pragma unroll
            for (int t = 0; t < 16; t++) pa.s[t] = 0;
        }
        *(uint4*)&As[r][half * 16]     = pa.q[0];
        *(uint4*)&As[r][half * 16 + 8] = pa.q[1];
        // ---- stage B: 64 rows x 32 k, hi (threads 0..63) / lo (threads 64..127)
        if (tid < 128) {
            int row = tid & 63;
            const unsigned short* bp = ((tid < 64) ? Bhi : Blo) + (size_t)row * 256;
            unsigned short (*bs)[32] = (tid < 64) ? BsH : BsL;
            *(uint4*)&bs[row][0]  = *(const uint4*)(bp + k0);
            *(uint4*)&bs[row][8]  = *(const uint4*)(bp + k0 + 8);
            *(uint4*)&bs[row][16] = *(const uint4*)(bp + k0 + 16);
            *(uint4*)&bs[row][24] = *(const uint4*)(bp + k0 + 24);
        }
        __syncthreads();

        short8 af[4];
#pragma unroll
        for (int mt = 0; mt < 4; mt++) af[mt] = *(short8*)&As[wm * 64 + mt * 16 + cl][q8];
        // split A into hi/lo? A already bf16 (exact): single value. 3-term only for B's split.
#pragma unroll
        for (int nt = 0; nt < 2; nt++) {
            short8 bh = *(short8*)&BsH[wn * 32 + nt * 16 + cl][q8];
            short8 bl = *(short8*)&BsL[wn * 32 + nt * 16 + cl][q8];
#pragma unroll
            for (int mt = 0; mt < 4; mt++) {
                acc[mt][nt] = __builtin_amdgcn_mfma_f32_16x16x32_bf16(af[mt], bh, acc[mt][nt], 0, 0, 0);
                acc[mt][nt] = __builtin_amdgcn_mfma_f32_16x16x32_bf16(af[mt], bl, acc[mt][nt], 0, 0, 0);
            }
        }
        __syncthreads();
    }

#pragma unroll
    for (int mt = 0; mt < 4; mt++) {
#pragma unroll
        for (int reg = 0; reg < 4; reg++) {
            int gr = rowBase + wm * 64 + mt * 16 + quad * 4 + reg;
            if (gr < M) {
#pragma unroll
                for (int nt = 0; nt < 2; nt++) {
                    H2[(size_t)gr * 64 + wn * 32 + nt * 16 + cl] = f2bf(acc[mt][nt][reg]);
                }
            }
        }
    }
}

// ---------------------------------------------------------------- SpMM2 (F=64): half-wave per row, bf16 gather
__global__ __launch_bounds__(256) void agg2_kernel(const unsigned short* __restrict__ H2,
                                                   const int* __restrict__ rs,
                                                   const int2* __restrict__ edges,
                                                   float* __restrict__ H3, int n) {
    int w = threadIdx.x >> 6, lane = threadIdx.x & 63;
    int half = lane >> 5, sub = lane & 31;
    int i = blockIdx.x * 8 + w * 2 + half;
    if (i >= n) return;
    int start = rs[i], end = rs[i + 1];
    int fo = sub << 1;
    float accx = 0.f, accy = 0.f;
    int j = start;
    for (; j + 4 <= end; j += 4) {
        int2 e[4];
        ushortx2 u[4];
#pragma unroll
        for (int t = 0; t < 4; t++) e[t] = edges[j + t];
#pragma unroll
        for (int t = 0; t < 4; t++)
            u[t] = *(const ushortx2*)(H2 + (size_t)e[t].x * 64 + fo);
#pragma unroll
        for (int t = 0; t < 4; t++) {
            float v = __int_as_float(e[t].y);
            accx += v * bf2f(u[t].x);
            accy += v * bf2f(u[t].y);
        }
    }
    for (; j < end; j++) {
        int2 e = edges[j];
        float v = __int_as_float(e.y);
        ushortx2 u = *(const ushortx2*)(H2 + (size_t)e.x * 64 + fo);
        accx += v * bf2f(u.x);
        accy += v * bf2f(u.y);
    }
    float2 o;
    o.x = fmaxf(accx, 0.f);
    o.y = fmaxf(accy, 0.f);
    *(float2*)(H3 + (size_t)i * 64 + fo) = o;
}

// ---------------------------------------------------------------- column stats F=64
__global__ __launch_bounds__(256) void colstats2_kernel(const float* __restrict__ H3,
                                                        float* __restrict__ sums,
                                                        float* __restrict__ sumsq,
                                                        int n, int rpb) {
    int c = threadIdx.x & 63, rsub = threadIdx.x >> 6;
    int base = blockIdx.x * rpb;
    int r1 = min(base + rpb, n);
    float s = 0.f, q = 0.f;
    for (int rr = base + rsub; rr < r1; rr += 4) {
        float v = H3[(size_t)rr * 64 + c];
        s += v; q += v * v;
    }
    atomicAdd(&sums[c], s);
    atomicAdd(&sumsq[c], q);
}

__global__ void bnapply_kernel(float* __restrict__ out, const float* __restrict__ scale,
                               const float* __restrict__ shift, int total) {
    int idx = blockIdx.x * 256 + threadIdx.x;
    if (idx < total) {
        int c = idx & 63;
        out[idx] = out[idx] * scale[c] + shift[c];
    }
}

// ---------------------------------------------------------------- launch
extern "C" void kernel_launch(void* const* d_in, const int* in_sizes, int n_in,
                              void* d_out, int out_size, void* d_ws, size_t ws_size,
                              hipStream_t stream) {
    const float* x    = (const float*)d_in[0];
    const int*   erow = (const int*)d_in[1];
    const int*   ecol = (const int*)d_in[2];
    const float* ev   = (const float*)d_in[3];
    const float* W1   = (const float*)d_in[4];
    const float* g1   = (const float*)d_in[5];
    const float* b1   = (const float*)d_in[6];
    const float* W2   = (const float*)d_in[7];
    const float* g2   = (const float*)d_in[8];
    const float* b2   = (const float*)d_in[9];
    float* out = (float*)d_out;

    int n = in_sizes[0] / 512;   // 100000
    int E = in_sizes[1];         // 3200000
    int nb = (n + 127) >> 7;     // 782 buckets of 128 rows
    int chunk = 16384;
    int nchunks = (E + chunk - 1) / chunk;

    char* ws = (char*)d_ws;
    size_t off = 0;
    auto alloc = [&](size_t bytes) { size_t o = off; off += (bytes + 255) & ~(size_t)255; return o; };

    int*   hist2        = (int*)(ws + alloc((size_t)nb * 8 * 4));
    int*   cursor2      = (int*)(ws + alloc((size_t)nb * 8 * 4));
    int*   bucket_start = (int*)(ws + alloc((size_t)(nb + 1) * 4));
    int*   row_start    = (int*)(ws + alloc((size_t)(n + 1) * 4));
    int2*  tmp          = (int2*)(ws + alloc((size_t)E * 8));
    int2*  edges        = (int2*)(ws + alloc((size_t)E * 8));
    unsigned short* h0  = (unsigned short*)(ws + alloc((size_t)n * 256 * 2));
    unsigned short* h1  = (unsigned short*)(ws + alloc((size_t)n * 256 * 2));
    unsigned short* h2  = (unsigned short*)(ws + alloc((size_t)n * 64 * 2));
    unsigned short* w1hi = (unsigned short*)(ws + alloc((size_t)256 * 512 * 2));
    unsigned short* w1lo = (unsigned short*)(ws + alloc((size_t)256 * 512 * 2));
    unsigned short* w2hi = (unsigned short*)(ws + alloc((size_t)64 * 256 * 2));
    unsigned short* w2lo = (unsigned short*)(ws + alloc((size_t)64 * 256 * 2));
    float* stats        = (float*)(ws + alloc(2048 * 4));
    float* sums1  = stats;
    float* sumsq1 = stats + 256;
    float* sums2  = stats + 512;
    float* sumsq2 = stats + 576;
    float* scale1 = stats + 640;
    float* shift1 = stats + 896;
    float* scale2 = stats + 1152;
    float* shift2 = stats + 1216;

    float invN = 1.0f / (float)n;

    // 1. zero hist2 + stat accumulators
    zero_kernel<<<dim3((nb * 8 + 255) / 256), dim3(256), 0, stream>>>(hist2, stats, nb * 8, 640);
    // 2. bucketed histogram (LDS-preaggregated)
    bucket_hist_kernel<<<dim3(nchunks), dim3(256), 0, stream>>>(erow, hist2, E, chunk, nb);
    // 3. scan -> per-(bucket,group) cursors + bucket_start
    bucket_scan_kernel<<<dim3(1), dim3(1024), 0, stream>>>(hist2, cursor2, bucket_start, row_start, nb, n, E);
    // 4. pass 1: append into bucket sub-regions
    pass1_scatter_kernel<<<dim3(nchunks), dim3(256), 0, stream>>>(erow, ecol, ev, cursor2, tmp, E, chunk);
    // 5. pass 2: exact CSR placement within 32KB windows + row_start
    pass2_kernel<<<dim3(nb), dim3(256), 0, stream>>>(tmp, bucket_start, row_start, edges, n);
    // 6. weight prep (split bf16, transposed)
    prep_w1_kernel<<<dim3(512), dim3(256), 0, stream>>>(W1, w1hi, w1lo);
    prep_w2_kernel<<<dim3(64), dim3(256), 0, stream>>>(W2, w2hi, w2lo);
    // 7. h0(bf16) = x @ W1  (split-bf16 MFMA, A read once)
    gemm1_mfma_kernel<<<dim3((n + 127) / 128), dim3(256), 0, stream>>>(x, w1hi, w1lo, h0, n);
    // 8. h1(bf16) = relu(spmm(h0))
    agg1_kernel<<<dim3((n + 3) / 4), dim3(256), 0, stream>>>(h0, row_start, edges, h1, n);
    // 9. BN1 stats (bf16 input)
    colstats1_kernel<<<dim3(400), dim3(256), 0, stream>>>(h1, sums1, sumsq1, n, (n + 399) / 400);
    // 10. BN1 params
    bnparams_kernel<<<dim3(1), dim3(256), 0, stream>>>(sums1, sumsq1, g1, b1, scale1, shift1, 256, invN);
    // 11. h2(bf16) = relu(bn1(h1)) @ W2  (MFMA, fused BN+relu staging)
    gemm2_mfma_kernel<<<dim3((n + 127) / 128), dim3(256), 0, stream>>>(h1, w2hi, w2lo, scale1, shift1, h2, n);
    // 12. out_pre = relu(spmm(h2))  (written into d_out)
    agg2_kernel<<<dim3((n + 7) / 8), dim3(256), 0, stream>>>(h2, row_start, edges, out, n);
    // 13. BN2 stats
    colstats2_kernel<<<dim3(200), dim3(256), 0, stream>>>(out, sums2, sumsq2, n, (n + 199) / 200);
    // 14. BN2 params
    bnparams_kernel<<<dim3(1), dim3(64), 0, stream>>>(sums2, sumsq2, g2, b2, scale2, shift2, 64, invN);
    // 15. in-place BN apply on d_out
    bnapply_kernel<<<dim3((n * 64 + 255) / 256), dim3(256), 0, stream>>>(out, scale2, shift2, n * 64);

    (void)n_in; (void)out_size; (void)ws_size;
}